// Round 1
// baseline (358.559 us; speedup 1.0000x reference)
//
#include <hip/hip_runtime.h>
#include <math.h>

#define NQ 14
#define NSTATE (1 << NQ)        // 16384
#define NPAIR  (NSTATE / 2)     // 8192
#define DEPTH  6
#define NT     512              // threads per block (8 waves)

__global__ __launch_bounds__(NT)
void vqc_kernel(const float* __restrict__ X,    // (512,14)
                const float* __restrict__ TH,   // (6,14)
                const float* __restrict__ A,    // (14,28)
                const float* __restrict__ Bc,   // (14,28)
                const float* __restrict__ D,    // (14,8)
                float* __restrict__ out)        // (512,2)
{
    __shared__ float2 st[NSTATE];               // 128 KiB state
    __shared__ float  red[2 * (NT / 64)];

    const int tid = threadIdx.x;
    const int b   = blockIdx.x;

    // ---- init: H-layer + 14 per-sample RYs fused into a product state ----
    float f0[NQ], f1[NQ];
#pragma unroll
    for (int w = 0; w < NQ; ++w) {
        float half = 0.5f * X[b * NQ + w];
        float s, c;
        sincosf(half, &s, &c);
        f0[w] = c - s;          // factor when bit_w == 0
        f1[w] = c + s;          // factor when bit_w == 1
    }
    const float amp = 1.0f / 128.0f;            // 1/sqrt(2^14)
    for (int n = tid; n < NSTATE; n += NT) {
        float v = amp;
#pragma unroll
        for (int w = 0; w < NQ; ++w)
            v *= ((n >> (NQ - 1 - w)) & 1) ? f1[w] : f0[w];
        st[n] = make_float2(v, 0.0f);
    }
    __syncthreads();

    // ---- VQC layers ----
    for (int k = 0; k < DEPTH; ++k) {
        // even CNOTs (ctrl 0,2,...,12 ; tgt = ctrl+1) fused: ctrl bits 0x2AAA
        for (int n = tid; n < NSTATE; n += NT) {
            int m = n ^ ((n & 0x2AAA) >> 1);
            if (m > n) { float2 t = st[n]; st[n] = st[m]; st[m] = t; }
        }
        __syncthreads();
        // odd CNOTs (ctrl 1,3,...,11) fused: ctrl bits 0x1554
        for (int n = tid; n < NSTATE; n += NT) {
            int m = n ^ ((n & 0x1554) >> 1);
            if (m > n) { float2 t = st[n]; st[n] = st[m]; st[m] = t; }
        }
        __syncthreads();
        // RY layer, shared angles theta[k][w]
        for (int w = 0; w < NQ; ++w) {
            float half = 0.5f * TH[k * NQ + w];
            float s, c;
            sincosf(half, &s, &c);
            const int p   = NQ - 1 - w;         // bit position of wire w
            const int low = (1 << p) - 1;
            for (int pr = tid; pr < NPAIR; pr += NT) {
                int i0 = ((pr & ~low) << 1) | (pr & low);
                int i1 = i0 | (1 << p);
                float2 a0 = st[i0], a1 = st[i1];
                st[i0] = make_float2(c * a0.x - s * a1.x, c * a0.y - s * a1.y);
                st[i1] = make_float2(s * a0.x + c * a1.x, s * a0.y + c * a1.y);
            }
            __syncthreads();
        }
    }

    // ---- expectations for q = 0 (wires 0,1,2) and q = 1 (wires 1,2,3) ----
    float e[2];
#pragma unroll
    for (int q = 0; q < 2; ++q) {
        const int shift = 11 - q;               // 3 observable bits at [shift+2 .. shift]
        float dg[8];
#pragma unroll
        for (int i = 0; i < 7; ++i) dg[i] = 2.0f * D[q * 8 + i + 1];
        dg[7] = 0.0f;
        float acc = 0.0f;
        const int lowmask = (1 << shift) - 1;
        for (int r = tid; r < NSTATE / 8; r += NT) {
            int base = ((r >> shift) << (shift + 3)) | (r & lowmask);
            float2 psi[8];
#pragma unroll
            for (int i = 0; i < 8; ++i) psi[i] = st[base + (i << shift)];
#pragma unroll
            for (int i = 0; i < 8; ++i)
                acc += dg[i] * (psi[i].x * psi[i].x + psi[i].y * psi[i].y);
            int kk = 0;
#pragma unroll
            for (int i = 1; i < 8; ++i) {
#pragma unroll
                for (int j = 0; j < i; ++j, ++kk) {
                    float pr = psi[i].x * psi[j].x + psi[i].y * psi[j].y;
                    float qi = psi[i].x * psi[j].y - psi[i].y * psi[j].x;
                    acc += 2.0f * (A[q * 28 + kk] * pr - Bc[q * 28 + kk] * qi);
                }
            }
        }
        e[q] = acc;
    }

    // ---- block reduction (two scalars) ----
    float v0 = e[0], v1 = e[1];
#pragma unroll
    for (int o = 32; o > 0; o >>= 1) {
        v0 += __shfl_down(v0, o);
        v1 += __shfl_down(v1, o);
    }
    if ((tid & 63) == 0) {
        red[(tid >> 6) * 2]     = v0;
        red[(tid >> 6) * 2 + 1] = v1;
    }
    __syncthreads();
    if (tid == 0) {
        float s0 = 0.0f, s1 = 0.0f;
#pragma unroll
        for (int i = 0; i < NT / 64; ++i) { s0 += red[i * 2]; s1 += red[i * 2 + 1]; }
        out[b * 2 + 0] = s0;
        out[b * 2 + 1] = s1;
    }
}

extern "C" void kernel_launch(void* const* d_in, const int* in_sizes, int n_in,
                              void* d_out, int out_size, void* d_ws, size_t ws_size,
                              hipStream_t stream) {
    const float* X  = (const float*)d_in[0];
    const float* TH = (const float*)d_in[1];
    const float* A  = (const float*)d_in[2];
    const float* Bc = (const float*)d_in[3];
    const float* D  = (const float*)d_in[4];
    float* out = (float*)d_out;
    vqc_kernel<<<512, NT, 0, stream>>>(X, TH, A, Bc, D, out);
}

// Round 2
// 227.178 us; speedup vs baseline: 1.5783x; 1.5783x over previous
//
#include <hip/hip_runtime.h>
#include <math.h>

#define NQ 14
#define NSTATE (1 << NQ)        // 16384
#define DEPTH  6
#define NT     1024             // 16 waves per block

// XOR swizzle on float2 index: spreads bit-strided accesses across banks
__device__ __forceinline__ int swz(int n) { return n ^ ((n >> 4) & 15); }

// In-register RY on group-bit JB over a 16-amplitude register block.
// psi[i] with bit JB == 0 is the a0 element (matches reference layout).
template <int JB>
__device__ __forceinline__ void ry16(float2 (&psi)[16], float c, float s) {
#pragma unroll
    for (int i = 0; i < 16; ++i) {
        if (!((i >> JB) & 1)) {
            const int i1 = i | (1 << JB);
            float2 a0 = psi[i], a1 = psi[i1];
            psi[i]  = make_float2(c * a0.x - s * a1.x, c * a0.y - s * a1.y);
            psi[i1] = make_float2(s * a0.x + c * a1.x, s * a0.y + c * a1.y);
        }
    }
}

__global__ __launch_bounds__(NT, 4)
void vqc_kernel(const float* __restrict__ X,    // (512,14)
                const float* __restrict__ TH,   // (6,14)
                const float* __restrict__ A,    // (14,28)
                const float* __restrict__ Bc,   // (14,28)
                const float* __restrict__ D,    // (14,8)
                float* __restrict__ out)        // (512,2)
{
    __shared__ float2 st[NSTATE];               // 128 KiB
    __shared__ float  red[2 * (NT / 64)];

    const int tid = threadIdx.x;
    const int b   = blockIdx.x;

    // ---- init: H-layer + 14 per-sample RYs fused into product state ----
    {
        float f0[NQ], f1[NQ];
#pragma unroll
        for (int w = 0; w < NQ; ++w) {
            float h = 0.5f * X[b * NQ + w], s, c;
            sincosf(h, &s, &c);
            f0[w] = c - s;
            f1[w] = c + s;
        }
        const float amp = 1.0f / 128.0f;
#pragma unroll
        for (int j = 0; j < NSTATE / NT; ++j) {   // 16 amps/thread
            int n = j * NT + tid;
            float v = amp;
#pragma unroll
            for (int w = 0; w < NQ; ++w)
                v *= ((n >> (NQ - 1 - w)) & 1) ? f1[w] : f0[w];
            st[swz(n)] = make_float2(v, 0.0f);
        }
    }
    __syncthreads();

    // ---- VQC layers: 4 register-blocked passes per layer ----
    for (int k = 0; k < DEPTH; ++k) {
        const float* th = TH + k * NQ;

        // P1: amplitude bits 0-3 (wires 13..10); gather applies both CNOT
        // ladders: value_new[n] = st_old[sigma_even(sigma_odd(n))]
        {
            float2 psi[16];
            const int base = tid * 16;
            int raddr[16];
#pragma unroll
            for (int i = 0; i < 16; ++i) {
                int n = base + i;
                int m = n ^ ((n & 0x1554) >> 1);   // odd CNOTs
                m ^= (m & 0x2AAA) >> 1;            // even CNOTs
                raddr[i] = swz(m);
            }
#pragma unroll
            for (int i = 0; i < 16; ++i) psi[i] = st[raddr[i]];
            __syncthreads();                       // all reads before any write
            float c0, s0, c1, s1, c2, s2, c3, s3;
            sincosf(0.5f * th[13], &s0, &c0);
            sincosf(0.5f * th[12], &s1, &c1);
            sincosf(0.5f * th[11], &s2, &c2);
            sincosf(0.5f * th[10], &s3, &c3);
            ry16<0>(psi, c0, s0);
            ry16<1>(psi, c1, s1);
            ry16<2>(psi, c2, s2);
            ry16<3>(psi, c3, s3);
#pragma unroll
            for (int i = 0; i < 16; ++i) st[swz(base + i)] = psi[i];
            __syncthreads();
        }

        // P2: bits 4-7 (wires 9..6). Same-slot RMW per thread: one barrier.
        {
            float2 psi[16];
            const int base = (tid >> 4) * 256 + (tid & 15);
#pragma unroll
            for (int i = 0; i < 16; ++i) psi[i] = st[swz(base + i * 16)];
            float c0, s0, c1, s1, c2, s2, c3, s3;
            sincosf(0.5f * th[9], &s0, &c0);
            sincosf(0.5f * th[8], &s1, &c1);
            sincosf(0.5f * th[7], &s2, &c2);
            sincosf(0.5f * th[6], &s3, &c3);
            ry16<0>(psi, c0, s0);
            ry16<1>(psi, c1, s1);
            ry16<2>(psi, c2, s2);
            ry16<3>(psi, c3, s3);
#pragma unroll
            for (int i = 0; i < 16; ++i) st[swz(base + i * 16)] = psi[i];
            __syncthreads();
        }

        // P3: bits 8-11 (wires 5..2)
        {
            float2 psi[16];
            const int base = (tid >> 8) * 4096 + (tid & 255);
#pragma unroll
            for (int i = 0; i < 16; ++i) psi[i] = st[swz(base + i * 256)];
            float c0, s0, c1, s1, c2, s2, c3, s3;
            sincosf(0.5f * th[5], &s0, &c0);
            sincosf(0.5f * th[4], &s1, &c1);
            sincosf(0.5f * th[3], &s2, &c2);
            sincosf(0.5f * th[2], &s3, &c3);
            ry16<0>(psi, c0, s0);
            ry16<1>(psi, c1, s1);
            ry16<2>(psi, c2, s2);
            ry16<3>(psi, c3, s3);
#pragma unroll
            for (int i = 0; i < 16; ++i) st[swz(base + i * 256)] = psi[i];
            __syncthreads();
        }

        // P4: bits 12-13 (wires 1,0); m bits 2-3 map to inert bits 10-11
        {
            float2 psi[16];
#pragma unroll
            for (int m = 0; m < 16; ++m) {
                int n = (m & 3) * 4096 + (m >> 2) * 1024 + tid;
                psi[m] = st[swz(n)];
            }
            float c0, s0, c1, s1;
            sincosf(0.5f * th[1], &s0, &c0);   // n-bit 12 <-> m-bit 0
            sincosf(0.5f * th[0], &s1, &c1);   // n-bit 13 <-> m-bit 1
            ry16<0>(psi, c0, s0);
            ry16<1>(psi, c1, s1);
#pragma unroll
            for (int m = 0; m < 16; ++m) {
                int n = (m & 3) * 4096 + (m >> 2) * 1024 + tid;
                st[swz(n)] = psi[m];
            }
            __syncthreads();
        }
    }

    // ---- expectations: q=0 (wires 0,1,2) and q=1 (wires 1,2,3) ----
    float e[2];
#pragma unroll
    for (int q = 0; q < 2; ++q) {
        const int shift = 11 - q;
        float dg[8];
#pragma unroll
        for (int i = 0; i < 7; ++i) dg[i] = 2.0f * D[q * 8 + i + 1];
        dg[7] = 0.0f;
        float acc = 0.0f;
        const int lowmask = (1 << shift) - 1;
        for (int r = tid; r < NSTATE / 8; r += NT) {   // 2 iterations
            int base = ((r >> shift) << (shift + 3)) | (r & lowmask);
            float2 psi[8];
#pragma unroll
            for (int i = 0; i < 8; ++i) psi[i] = st[swz(base + (i << shift))];
#pragma unroll
            for (int i = 0; i < 8; ++i)
                acc += dg[i] * (psi[i].x * psi[i].x + psi[i].y * psi[i].y);
            int kk = 0;
#pragma unroll
            for (int i = 1; i < 8; ++i) {
#pragma unroll
                for (int j = 0; j < i; ++j, ++kk) {
                    float pr = psi[i].x * psi[j].x + psi[i].y * psi[j].y;
                    float qi = psi[i].x * psi[j].y - psi[i].y * psi[j].x;
                    acc += 2.0f * (A[q * 28 + kk] * pr - Bc[q * 28 + kk] * qi);
                }
            }
        }
        e[q] = acc;
    }

    // ---- block reduction ----
    float v0 = e[0], v1 = e[1];
#pragma unroll
    for (int o = 32; o > 0; o >>= 1) {
        v0 += __shfl_down(v0, o);
        v1 += __shfl_down(v1, o);
    }
    if ((tid & 63) == 0) {
        red[(tid >> 6) * 2]     = v0;
        red[(tid >> 6) * 2 + 1] = v1;
    }
    __syncthreads();
    if (tid == 0) {
        float s0 = 0.0f, s1 = 0.0f;
#pragma unroll
        for (int i = 0; i < NT / 64; ++i) { s0 += red[i * 2]; s1 += red[i * 2 + 1]; }
        out[b * 2 + 0] = s0;
        out[b * 2 + 1] = s1;
    }
}

extern "C" void kernel_launch(void* const* d_in, const int* in_sizes, int n_in,
                              void* d_out, int out_size, void* d_ws, size_t ws_size,
                              hipStream_t stream) {
    const float* X  = (const float*)d_in[0];
    const float* TH = (const float*)d_in[1];
    const float* A  = (const float*)d_in[2];
    const float* Bc = (const float*)d_in[3];
    const float* D  = (const float*)d_in[4];
    float* out = (float*)d_out;
    vqc_kernel<<<512, NT, 0, stream>>>(X, TH, A, Bc, D, out);
}

// Round 3
// 109.090 us; speedup vs baseline: 3.2868x; 2.0825x over previous
//
#include <hip/hip_runtime.h>
#include <math.h>

#define NQ 14
#define NSTATE (1 << NQ)        // 16384
#define DEPTH  6
#define NT     1024             // 16 waves per block

// XOR swizzle on float2 index: spreads bit-strided accesses across banks
__device__ __forceinline__ int swz(int n) { return n ^ ((n >> 4) & 15); }

// In-register RY on psi-index bit JB over an 8-amplitude block.
template <int JB>
__device__ __forceinline__ void ry8(float2 (&psi)[8], float c, float s) {
#pragma unroll
    for (int i = 0; i < 8; ++i) {
        if (!((i >> JB) & 1)) {
            const int i1 = i | (1 << JB);
            float2 a0 = psi[i], a1 = psi[i1];
            psi[i]  = make_float2(c * a0.x - s * a1.x, c * a0.y - s * a1.y);
            psi[i1] = make_float2(s * a0.x + c * a1.x, s * a0.y + c * a1.y);
        }
    }
}

// RMW pass rotating amplitude-index bits P0<P1<P2 (psi bit j <-> n bit Pj).
// Two half-state chunks; chunks are disjoint in the top hole bit -> 1 barrier.
template <int P0, int P1, int P2>
__device__ __forceinline__ void pass_rmw(float2* st, int tid,
                                         float c0, float s0,
                                         float c1, float s1,
                                         float c2, float s2) {
#pragma unroll
    for (int q = 0; q < 2; ++q) {
        int x = (q << 10) | tid;                 // 11 payload bits
        int n = x & ((1 << P0) - 1);
        x >>= P0;
        n |= (x & ((1 << (P1 - P0 - 1)) - 1)) << (P0 + 1);
        x >>= (P1 - P0 - 1);
        n |= (x & ((1 << (P2 - P1 - 1)) - 1)) << (P1 + 1);
        x >>= (P2 - P1 - 1);
        n |= x << (P2 + 1);
        float2 psi[8];
#pragma unroll
        for (int i = 0; i < 8; ++i) {
            int idx = n | ((i & 1) << P0) | (((i >> 1) & 1) << P1) | (((i >> 2) & 1) << P2);
            psi[i] = st[swz(idx)];
        }
        ry8<0>(psi, c0, s0);
        ry8<1>(psi, c1, s1);
        ry8<2>(psi, c2, s2);
#pragma unroll
        for (int i = 0; i < 8; ++i) {
            int idx = n | ((i & 1) << P0) | (((i >> 1) & 1) << P1) | (((i >> 2) & 1) << P2);
            st[swz(idx)] = psi[i];
        }
    }
    __syncthreads();
}

// Gather pass: applies both CNOT ladders via permuted read (sigma preserves
// bit 13 -> chunks by bit 13 are independent), then rotates bits 0,1,2.
__device__ __forceinline__ void pass_cnot(float2* st, int tid,
                                          float c0, float s0,
                                          float c1, float s1,
                                          float c2, float s2) {
#pragma unroll
    for (int q = 0; q < 2; ++q) {
        const int base = (((q << 10) | tid) << 3);
        float2 psi[8];
#pragma unroll
        for (int i = 0; i < 8; ++i) {
            int nn = base | i;
            int m = nn ^ ((nn & 0x1554) >> 1);   // odd CNOTs
            m ^= (m & 0x2AAA) >> 1;              // even CNOTs
            psi[i] = st[swz(m)];
        }
        __syncthreads();                          // chunk reads before chunk writes
        ry8<0>(psi, c0, s0);
        ry8<1>(psi, c1, s1);
        ry8<2>(psi, c2, s2);
#pragma unroll
        for (int i = 0; i < 8; ++i) st[swz(base | i)] = psi[i];
    }
    __syncthreads();
}

__global__ __launch_bounds__(NT)
void vqc_kernel(const float* __restrict__ X,    // (512,14)
                const float* __restrict__ TH,   // (6,14)
                const float* __restrict__ A,    // (14,28)
                const float* __restrict__ Bc,   // (14,28)
                const float* __restrict__ D,    // (14,8)
                float* __restrict__ out)        // (512,2)
{
    __shared__ float2 st[NSTATE];               // 128 KiB
    __shared__ float  red[2 * (NT / 64)];

    const int tid = threadIdx.x;
    const int b   = blockIdx.x;

    // ---- init: H-layer + 14 per-sample RYs fused into product state ----
    {
        float f0[NQ], f1[NQ];
#pragma unroll
        for (int w = 0; w < NQ; ++w) {
            float s, c;
            __sincosf(0.5f * X[b * NQ + w], &s, &c);
            f0[w] = c - s;
            f1[w] = c + s;
        }
        const float amp = 1.0f / 128.0f;
#pragma unroll
        for (int j = 0; j < NSTATE / NT; ++j) {
            int n = j * NT + tid;
            float v = amp;
#pragma unroll
            for (int w = 0; w < NQ; ++w)
                v *= ((n >> (NQ - 1 - w)) & 1) ? f1[w] : f0[w];
            st[swz(n)] = make_float2(v, 0.0f);
        }
    }
    __syncthreads();

    // ---- VQC layers: CNOT-fused gather + 4 RMW passes per layer ----
    // wire w lives at amplitude bit (13 - w)
    for (int k = 0; k < DEPTH; ++k) {
        const float* th = TH + k * NQ;
        float c0, s0, c1, s1, c2, s2;

        __sincosf(0.5f * th[13], &s0, &c0);
        __sincosf(0.5f * th[12], &s1, &c1);
        __sincosf(0.5f * th[11], &s2, &c2);
        pass_cnot(st, tid, c0, s0, c1, s1, c2, s2);            // bits 0,1,2

        __sincosf(0.5f * th[10], &s0, &c0);
        __sincosf(0.5f * th[9],  &s1, &c1);
        __sincosf(0.5f * th[8],  &s2, &c2);
        pass_rmw<3, 4, 5>(st, tid, c0, s0, c1, s1, c2, s2);

        __sincosf(0.5f * th[7], &s0, &c0);
        __sincosf(0.5f * th[6], &s1, &c1);
        __sincosf(0.5f * th[5], &s2, &c2);
        pass_rmw<6, 7, 8>(st, tid, c0, s0, c1, s1, c2, s2);

        __sincosf(0.5f * th[4], &s0, &c0);
        __sincosf(0.5f * th[3], &s1, &c1);
        __sincosf(0.5f * th[2], &s2, &c2);
        pass_rmw<9, 10, 11>(st, tid, c0, s0, c1, s1, c2, s2);

        __sincosf(0.5f * th[1], &s1, &c1);
        __sincosf(0.5f * th[0], &s2, &c2);
        pass_rmw<11, 12, 13>(st, tid, 1.0f, 0.0f, c1, s1, c2, s2); // bit 11 passive
    }

    // ---- expectations: q=0 (wires 0,1,2) and q=1 (wires 1,2,3) ----
    float e[2];
#pragma unroll
    for (int q = 0; q < 2; ++q) {
        const int shift = 11 - q;
        float dg[8];
#pragma unroll
        for (int i = 0; i < 7; ++i) dg[i] = 2.0f * D[q * 8 + i + 1];
        dg[7] = 0.0f;
        float acc = 0.0f;
        const int lowmask = (1 << shift) - 1;
        for (int r = tid; r < NSTATE / 8; r += NT) {   // 2 iterations
            int base = ((r >> shift) << (shift + 3)) | (r & lowmask);
            float2 psi[8];
#pragma unroll
            for (int i = 0; i < 8; ++i) psi[i] = st[swz(base + (i << shift))];
#pragma unroll
            for (int i = 0; i < 8; ++i)
                acc += dg[i] * (psi[i].x * psi[i].x + psi[i].y * psi[i].y);
            int kk = 0;
#pragma unroll
            for (int i = 1; i < 8; ++i) {
#pragma unroll
                for (int j = 0; j < i; ++j, ++kk) {
                    float pr = psi[i].x * psi[j].x + psi[i].y * psi[j].y;
                    float qi = psi[i].x * psi[j].y - psi[i].y * psi[j].x;
                    acc += 2.0f * (A[q * 28 + kk] * pr - Bc[q * 28 + kk] * qi);
                }
            }
        }
        e[q] = acc;
    }

    // ---- block reduction ----
    float v0 = e[0], v1 = e[1];
#pragma unroll
    for (int o = 32; o > 0; o >>= 1) {
        v0 += __shfl_down(v0, o);
        v1 += __shfl_down(v1, o);
    }
    if ((tid & 63) == 0) {
        red[(tid >> 6) * 2]     = v0;
        red[(tid >> 6) * 2 + 1] = v1;
    }
    __syncthreads();
    if (tid == 0) {
        float s0 = 0.0f, s1 = 0.0f;
#pragma unroll
        for (int i = 0; i < NT / 64; ++i) { s0 += red[i * 2]; s1 += red[i * 2 + 1]; }
        out[b * 2 + 0] = s0;
        out[b * 2 + 1] = s1;
    }
}

extern "C" void kernel_launch(void* const* d_in, const int* in_sizes, int n_in,
                              void* d_out, int out_size, void* d_ws, size_t ws_size,
                              hipStream_t stream) {
    const float* X  = (const float*)d_in[0];
    const float* TH = (const float*)d_in[1];
    const float* A  = (const float*)d_in[2];
    const float* Bc = (const float*)d_in[3];
    const float* D  = (const float*)d_in[4];
    float* out = (float*)d_out;
    vqc_kernel<<<512, NT, 0, stream>>>(X, TH, A, Bc, D, out);
}

// Round 4
// 83.540 us; speedup vs baseline: 4.2921x; 1.3058x over previous
//
#include <hip/hip_runtime.h>
#include <math.h>

#define NQ 14
#define NSTATE (1 << NQ)        // 16384
#define DEPTH  6
#define NT     1024             // 16 waves/block; 2 blocks/CU (64 KiB LDS each)

// word-index swizzle: XOR bits 6,7,8 into 2,3,4 -> conflict-free for all passes
__device__ __forceinline__ int swz(int n) { return n ^ ((n >> 4) & 28); }

// fused CNOT ladders (even after odd): m = sigma_e(sigma_o(n))
__device__ __forceinline__ int sigma(int n) {
    int m = n ^ ((n & 0x1554) >> 1);
    return m ^ ((m & 0x2AAA) >> 1);
}

// RY on psi-index bit JB over a 16-amp real register block
template <int JB>
__device__ __forceinline__ void ry16(float (&p)[16], float c, float s) {
#pragma unroll
    for (int i = 0; i < 16; ++i) {
        if (!((i >> JB) & 1)) {
            const int i1 = i | (1 << JB);
            float a0 = p[i], a1 = p[i1];
            p[i]  = c * a0 - s * a1;
            p[i1] = s * a0 + c * a1;
        }
    }
}

// RMW pass rotating the 4 amplitude-index bits at [SH, SH+4)
template <int SH, bool ROT01>
__device__ __forceinline__ void pass_rmw(float* st, int t,
                                         float c0, float s0, float c1, float s1,
                                         float c2, float s2, float c3, float s3) {
    const int n = (t & ((1 << SH) - 1)) | ((t >> SH) << (SH + 4));
    float p[16];
#pragma unroll
    for (int i = 0; i < 16; ++i) p[i] = st[swz(n | (i << SH))];
    if (ROT01) {
        ry16<0>(p, c0, s0);
        ry16<1>(p, c1, s1);
    }
    ry16<2>(p, c2, s2);
    ry16<3>(p, c3, s3);
#pragma unroll
    for (int i = 0; i < 16; ++i) st[swz(n | (i << SH))] = p[i];
    __syncthreads();
}

// CNOT-fused pass (layers k>=1): sigma maps aligned 16-blocks to aligned
// 16-blocks, so read 4x float4 from the source block, register-permute by the
// in-block affine map, rotate bits 0-3, write own block vectorized.
__device__ __forceinline__ void pass_cnot(float* st, int t,
                                          float c0, float s0, float c1, float s1,
                                          float c2, float s2, float c3, float s3) {
    const int bstart = sigma(t << 4) & ~15;
    float tmp[16];
#pragma unroll
    for (int g = 0; g < 4; ++g)
        *(float4*)&tmp[g * 4] = *(const float4*)&st[swz(bstart + g * 4)];
    const int t0 = t & 1;                        // n bit 4
    float p[16];
#pragma unroll
    for (int i = 0; i < 16; ++i) {
        const int i0 = i & 1, i1 = (i >> 1) & 1, i2 = (i >> 2) & 1, i3 = (i >> 3) & 1;
        const int s = (i0 ^ i1 ^ i2) | ((i1 ^ i2) << 1) | ((i2 ^ i3) << 2) | (i3 << 3);
        p[i] = t0 ? tmp[s ^ 12] : tmp[s];        // sigma_low(i) = s ^ (t0*12)
    }
    __syncthreads();                             // all reads before any write
    ry16<0>(p, c0, s0);
    ry16<1>(p, c1, s1);
    ry16<2>(p, c2, s2);
    ry16<3>(p, c3, s3);
#pragma unroll
    for (int g = 0; g < 4; ++g)
        *(float4*)&st[swz((t << 4) + g * 4)] = *(const float4*)&p[g * 4];
    __syncthreads();
}

__global__ __launch_bounds__(NT, 8)
void vqc_kernel(const float* __restrict__ X,    // (512,14)
                const float* __restrict__ TH,   // (6,14)
                const float* __restrict__ A,    // (14,28)
                const float* __restrict__ Bc,   // (14,28)  (unused: state is real)
                const float* __restrict__ D,    // (14,8)
                float* __restrict__ out)        // (512,2)
{
    __shared__ __align__(16) float st[NSTATE];  // 64 KiB real state
    __shared__ float red[2 * (NT / 64)];

    const int t = threadIdx.x;
    const int b = blockIdx.x;

    // ---- layer 0 P1: product-state init (H + data RYs) evaluated directly at
    //      sigma(n), then RY on bits 0-3. No LDS read, no init sweep. ----
    {
        float gg0[14], gg1[14];                 // factor by n-bit position j (wire 13-j)
#pragma unroll
        for (int j = 0; j < 14; ++j) {
            float s, c;
            __sincosf(0.5f * X[b * NQ + (13 - j)], &s, &c);
            gg0[j] = c - s;
            gg1[j] = c + s;
        }
        const int m = sigma(t << 4);
        float sh = 1.0f / 128.0f;               // shared partial: m bits 4..13
#pragma unroll
        for (int j = 4; j < 14; ++j) sh *= ((m >> j) & 1) ? gg1[j] : gg0[j];
        const int t0 = t & 1;                   // n bit 4
        const float f2a = t0 ? gg1[2] : gg0[2], f2b = t0 ? gg0[2] : gg1[2];
        const float f3a = t0 ? gg1[3] : gg0[3], f3b = t0 ? gg0[3] : gg1[3];
        float p[16];
#pragma unroll
        for (int i = 0; i < 16; ++i) {
            const int i0 = i & 1, i1 = (i >> 1) & 1, i2 = (i >> 2) & 1, i3 = (i >> 3) & 1;
            float v = sh;
            v *= (i0 ^ i1 ^ i2) ? gg1[0] : gg0[0];   // m bit 0
            v *= (i1 ^ i2)      ? gg1[1] : gg0[1];   // m bit 1
            v *= (i2 ^ i3)      ? f2b    : f2a;      // m bit 2 = i2^i3^t0
            v *= i3             ? f3b    : f3a;      // m bit 3 = i3^t0
            p[i] = v;
        }
        float c0, s0, c1, s1, c2, s2, c3, s3;
        __sincosf(0.5f * TH[13], &s0, &c0);
        __sincosf(0.5f * TH[12], &s1, &c1);
        __sincosf(0.5f * TH[11], &s2, &c2);
        __sincosf(0.5f * TH[10], &s3, &c3);
        ry16<0>(p, c0, s0);
        ry16<1>(p, c1, s1);
        ry16<2>(p, c2, s2);
        ry16<3>(p, c3, s3);
#pragma unroll
        for (int g = 0; g < 4; ++g)
            *(float4*)&st[swz((t << 4) + g * 4)] = *(const float4*)&p[g * 4];
    }
    __syncthreads();

    // ---- layers ----
    for (int k = 0; k < DEPTH; ++k) {
        const float* th = TH + k * NQ;
        float c0, s0, c1, s1, c2, s2, c3, s3;
        if (k > 0) {                            // layer 0's P1 done above
            __sincosf(0.5f * th[13], &s0, &c0);
            __sincosf(0.5f * th[12], &s1, &c1);
            __sincosf(0.5f * th[11], &s2, &c2);
            __sincosf(0.5f * th[10], &s3, &c3);
            pass_cnot(st, t, c0, s0, c1, s1, c2, s2, c3, s3);
        }
        __sincosf(0.5f * th[9], &s0, &c0);      // n bits 4..7 <-> wires 9..6
        __sincosf(0.5f * th[8], &s1, &c1);
        __sincosf(0.5f * th[7], &s2, &c2);
        __sincosf(0.5f * th[6], &s3, &c3);
        pass_rmw<4, true>(st, t, c0, s0, c1, s1, c2, s2, c3, s3);
        __sincosf(0.5f * th[5], &s0, &c0);      // n bits 8..11 <-> wires 5..2
        __sincosf(0.5f * th[4], &s1, &c1);
        __sincosf(0.5f * th[3], &s2, &c2);
        __sincosf(0.5f * th[2], &s3, &c3);
        pass_rmw<8, true>(st, t, c0, s0, c1, s1, c2, s2, c3, s3);
        __sincosf(0.5f * th[1], &s2, &c2);      // n bit 12 <-> wire 1
        __sincosf(0.5f * th[0], &s3, &c3);      // n bit 13 <-> wire 0
        pass_rmw<10, false>(st, t, 1.f, 0.f, 1.f, 0.f, c2, s2, c3, s3);
    }

    // ---- expectations (real state: B drops out) ----
    float e[2];
#pragma unroll
    for (int q = 0; q < 2; ++q) {
        const int shift = 11 - q;
        float dg[8];
#pragma unroll
        for (int i = 0; i < 7; ++i) dg[i] = 2.0f * D[q * 8 + i + 1];
        dg[7] = 0.0f;
        float acc = 0.0f;
        const int lowmask = (1 << shift) - 1;
        for (int r = t; r < NSTATE / 8; r += NT) {   // 2 iterations
            const int base = ((r >> shift) << (shift + 3)) | (r & lowmask);
            float ps[8];
#pragma unroll
            for (int i = 0; i < 8; ++i) ps[i] = st[swz(base + (i << shift))];
#pragma unroll
            for (int i = 0; i < 8; ++i) acc += dg[i] * ps[i] * ps[i];
            int kk = 0;
#pragma unroll
            for (int i = 1; i < 8; ++i)
#pragma unroll
                for (int j = 0; j < i; ++j, ++kk)
                    acc += 2.0f * A[q * 28 + kk] * ps[i] * ps[j];
        }
        e[q] = acc;
    }

    // ---- block reduction ----
    float v0 = e[0], v1 = e[1];
#pragma unroll
    for (int o = 32; o > 0; o >>= 1) {
        v0 += __shfl_down(v0, o);
        v1 += __shfl_down(v1, o);
    }
    if ((t & 63) == 0) {
        red[(t >> 6) * 2]     = v0;
        red[(t >> 6) * 2 + 1] = v1;
    }
    __syncthreads();
    if (t == 0) {
        float s0 = 0.0f, s1 = 0.0f;
#pragma unroll
        for (int i = 0; i < NT / 64; ++i) { s0 += red[i * 2]; s1 += red[i * 2 + 1]; }
        out[b * 2 + 0] = s0;
        out[b * 2 + 1] = s1;
    }
}

extern "C" void kernel_launch(void* const* d_in, const int* in_sizes, int n_in,
                              void* d_out, int out_size, void* d_ws, size_t ws_size,
                              hipStream_t stream) {
    const float* X  = (const float*)d_in[0];
    const float* TH = (const float*)d_in[1];
    const float* A  = (const float*)d_in[2];
    const float* Bc = (const float*)d_in[3];
    const float* D  = (const float*)d_in[4];
    float* out = (float*)d_out;
    vqc_kernel<<<512, NT, 0, stream>>>(X, TH, A, Bc, D, out);
}

// Round 5
// 68.727 us; speedup vs baseline: 5.2171x; 1.2155x over previous
//
#include <hip/hip_runtime.h>
#include <math.h>

#define NQ 14
#define NSTATE (1 << NQ)        // 16384
#define DEPTH  6
#define NT     1024             // 16 waves/block; target 2 blocks/CU (64 KiB LDS each)

// word-index swizzle: XOR bits 6,7,8 into 2,3,4
__device__ __forceinline__ int swz(int n) { return n ^ ((n >> 4) & 28); }

// fused CNOT ladders (even after odd): m = sigma_e(sigma_o(n))
__device__ __forceinline__ int sigma(int n) {
    int m = n ^ ((n & 0x1554) >> 1);
    return m ^ ((m & 0x2AAA) >> 1);
}

// RY on psi-index bit JB over a 16-amp real register block
template <int JB>
__device__ __forceinline__ void ry16(float (&p)[16], float c, float s) {
#pragma unroll
    for (int i = 0; i < 16; ++i) {
        if (!((i >> JB) & 1)) {
            const int i1 = i | (1 << JB);
            float a0 = p[i], a1 = p[i1];
            p[i]  = c * a0 - s * a1;
            p[i1] = s * a0 + c * a1;
        }
    }
}

// RMW pass rotating the 4 amplitude-index bits at [SH, SH+4)
template <int SH, bool ROT01>
__device__ __forceinline__ void pass_rmw(float* st, int t,
                                         float c0, float s0, float c1, float s1,
                                         float c2, float s2, float c3, float s3) {
    const int n = (t & ((1 << SH) - 1)) | ((t >> SH) << (SH + 4));
    float p[16];
#pragma unroll
    for (int i = 0; i < 16; ++i) p[i] = st[swz(n | (i << SH))];
    if (ROT01) {
        ry16<0>(p, c0, s0);
        ry16<1>(p, c1, s1);
    }
    ry16<2>(p, c2, s2);
    ry16<3>(p, c3, s3);
#pragma unroll
    for (int i = 0; i < 16; ++i) st[swz(n | (i << SH))] = p[i];
    __syncthreads();
}

// CNOT-fused pass (layers k>=1): sigma maps aligned 16-blocks to aligned
// 16-blocks; read 4x float4 from source block, register-permute, rotate, write.
__device__ __forceinline__ void pass_cnot(float* st, int t,
                                          float c0, float s0, float c1, float s1,
                                          float c2, float s2, float c3, float s3) {
    const int bstart = sigma(t << 4) & ~15;
    float tmp[16];
#pragma unroll
    for (int g = 0; g < 4; ++g)
        *(float4*)&tmp[g * 4] = *(const float4*)&st[swz(bstart + g * 4)];
    const int t0 = t & 1;                        // n bit 4
    float p[16];
#pragma unroll
    for (int i = 0; i < 16; ++i) {
        const int i0 = i & 1, i1 = (i >> 1) & 1, i2 = (i >> 2) & 1, i3 = (i >> 3) & 1;
        const int s = (i0 ^ i1 ^ i2) | ((i1 ^ i2) << 1) | ((i2 ^ i3) << 2) | (i3 << 3);
        p[i] = t0 ? tmp[s ^ 12] : tmp[s];        // sigma_low(i) = s ^ (t0*12)
    }
    __syncthreads();                             // all reads before any write
    ry16<0>(p, c0, s0);
    ry16<1>(p, c1, s1);
    ry16<2>(p, c2, s2);
    ry16<3>(p, c3, s3);
#pragma unroll
    for (int g = 0; g < 4; ++g)
        *(float4*)&st[swz((t << 4) + g * 4)] = *(const float4*)&p[g * 4];
    __syncthreads();
}

__global__ __launch_bounds__(NT, 4)
void vqc_kernel(const float* __restrict__ X,    // (512,14)
                const float* __restrict__ TH,   // (6,14)
                const float* __restrict__ A,    // (14,28)
                const float* __restrict__ Bc,   // (14,28)  (unused: state is real)
                const float* __restrict__ D,    // (14,8)
                float* __restrict__ out)        // (512,2)
{
    __shared__ __align__(16) float st[NSTATE];  // 64 KiB real state
    __shared__ float red[2 * (NT / 64)];

    const int t = threadIdx.x;
    const int b = blockIdx.x;

    // ---- layer 0 P1: product-state init (H + data RYs) evaluated directly at
    //      sigma(n), then RY on bits 0-3. Low register pressure: high-bit
    //      factors are folded into sh one at a time, never materialized. ----
    {
        const int m = sigma(t << 4);
        float sh = 1.0f / 128.0f;               // product over m bits 4..13
#pragma unroll
        for (int j = 4; j < 14; ++j) {
            float s, c;
            __sincosf(0.5f * X[b * NQ + (13 - j)], &s, &c);
            sh *= ((m >> j) & 1) ? (c + s) : (c - s);
        }
        float g0[4], g1[4];                     // low-bit factor pairs
#pragma unroll
        for (int j = 0; j < 4; ++j) {
            float s, c;
            __sincosf(0.5f * X[b * NQ + (13 - j)], &s, &c);
            g0[j] = c - s;
            g1[j] = c + s;
        }
        const int t0 = t & 1;                   // n bit 4
        const float f2a = t0 ? g1[2] : g0[2], f2b = t0 ? g0[2] : g1[2];
        const float f3a = t0 ? g1[3] : g0[3], f3b = t0 ? g0[3] : g1[3];
        float p[16];
#pragma unroll
        for (int i = 0; i < 16; ++i) {
            const int i0 = i & 1, i1 = (i >> 1) & 1, i2 = (i >> 2) & 1, i3 = (i >> 3) & 1;
            float v = sh;
            v *= (i0 ^ i1 ^ i2) ? g1[0] : g0[0];     // m bit 0
            v *= (i1 ^ i2)      ? g1[1] : g0[1];     // m bit 1
            v *= (i2 ^ i3)      ? f2b   : f2a;       // m bit 2 = i2^i3^t0
            v *= i3             ? f3b   : f3a;       // m bit 3 = i3^t0
            p[i] = v;
        }
        float c0, s0, c1, s1, c2, s2, c3, s3;
        __sincosf(0.5f * TH[13], &s0, &c0);
        __sincosf(0.5f * TH[12], &s1, &c1);
        __sincosf(0.5f * TH[11], &s2, &c2);
        __sincosf(0.5f * TH[10], &s3, &c3);
        ry16<0>(p, c0, s0);
        ry16<1>(p, c1, s1);
        ry16<2>(p, c2, s2);
        ry16<3>(p, c3, s3);
#pragma unroll
        for (int g = 0; g < 4; ++g)
            *(float4*)&st[swz((t << 4) + g * 4)] = *(const float4*)&p[g * 4];
    }
    __syncthreads();

    // ---- layers ----
    for (int k = 0; k < DEPTH; ++k) {
        const float* th = TH + k * NQ;
        float c0, s0, c1, s1, c2, s2, c3, s3;
        if (k > 0) {                            // layer 0's P1 done above
            __sincosf(0.5f * th[13], &s0, &c0);
            __sincosf(0.5f * th[12], &s1, &c1);
            __sincosf(0.5f * th[11], &s2, &c2);
            __sincosf(0.5f * th[10], &s3, &c3);
            pass_cnot(st, t, c0, s0, c1, s1, c2, s2, c3, s3);
        }
        __sincosf(0.5f * th[9], &s0, &c0);      // n bits 4..7 <-> wires 9..6
        __sincosf(0.5f * th[8], &s1, &c1);
        __sincosf(0.5f * th[7], &s2, &c2);
        __sincosf(0.5f * th[6], &s3, &c3);
        pass_rmw<4, true>(st, t, c0, s0, c1, s1, c2, s2, c3, s3);
        __sincosf(0.5f * th[5], &s0, &c0);      // n bits 8..11 <-> wires 5..2
        __sincosf(0.5f * th[4], &s1, &c1);
        __sincosf(0.5f * th[3], &s2, &c2);
        __sincosf(0.5f * th[2], &s3, &c3);
        pass_rmw<8, true>(st, t, c0, s0, c1, s1, c2, s2, c3, s3);
        __sincosf(0.5f * th[1], &s2, &c2);      // n bit 12 <-> wire 1
        __sincosf(0.5f * th[0], &s3, &c3);      // n bit 13 <-> wire 0
        pass_rmw<10, false>(st, t, 1.f, 0.f, 1.f, 0.f, c2, s2, c3, s3);
    }

    // ---- expectations (real state: B drops out) ----
    float e[2];
#pragma unroll
    for (int q = 0; q < 2; ++q) {
        const int shift = 11 - q;
        float dg[8];
#pragma unroll
        for (int i = 0; i < 7; ++i) dg[i] = 2.0f * D[q * 8 + i + 1];
        dg[7] = 0.0f;
        float acc = 0.0f;
        const int lowmask = (1 << shift) - 1;
        for (int r = t; r < NSTATE / 8; r += NT) {   // 2 iterations
            const int base = ((r >> shift) << (shift + 3)) | (r & lowmask);
            float ps[8];
#pragma unroll
            for (int i = 0; i < 8; ++i) ps[i] = st[swz(base + (i << shift))];
#pragma unroll
            for (int i = 0; i < 8; ++i) acc += dg[i] * ps[i] * ps[i];
            int kk = 0;
#pragma unroll
            for (int i = 1; i < 8; ++i)
#pragma unroll
                for (int j = 0; j < i; ++j, ++kk)
                    acc += 2.0f * A[q * 28 + kk] * ps[i] * ps[j];
        }
        e[q] = acc;
    }

    // ---- block reduction ----
    float v0 = e[0], v1 = e[1];
#pragma unroll
    for (int o = 32; o > 0; o >>= 1) {
        v0 += __shfl_down(v0, o);
        v1 += __shfl_down(v1, o);
    }
    if ((t & 63) == 0) {
        red[(t >> 6) * 2]     = v0;
        red[(t >> 6) * 2 + 1] = v1;
    }
    __syncthreads();
    if (t == 0) {
        float s0 = 0.0f, s1 = 0.0f;
#pragma unroll
        for (int i = 0; i < NT / 64; ++i) { s0 += red[i * 2]; s1 += red[i * 2 + 1]; }
        out[b * 2 + 0] = s0;
        out[b * 2 + 1] = s1;
    }
}

extern "C" void kernel_launch(void* const* d_in, const int* in_sizes, int n_in,
                              void* d_out, int out_size, void* d_ws, size_t ws_size,
                              hipStream_t stream) {
    const float* X  = (const float*)d_in[0];
    const float* TH = (const float*)d_in[1];
    const float* A  = (const float*)d_in[2];
    const float* Bc = (const float*)d_in[3];
    const float* D  = (const float*)d_in[4];
    float* out = (float*)d_out;
    vqc_kernel<<<512, NT, 0, stream>>>(X, TH, A, Bc, D, out);
}